// Round 9
// baseline (639.284 us; speedup 1.0000x reference)
//
#include <hip/hip_runtime.h>
#include <hip/hip_bf16.h>

#define NN 100000
#define EE 1600000
#define CH_STRIDE 1600000  // elements per 16-feature chunk buffer (NN*16)

typedef __attribute__((ext_vector_type(8))) short short8;
typedef __attribute__((ext_vector_type(4))) float f32x4;

__device__ __forceinline__ unsigned short f2bfu(float f) {
    __hip_bfloat16 h = __float2bfloat16(f);
    return *reinterpret_cast<unsigned short*>(&h);
}
__device__ __forceinline__ float bf2f(unsigned short u) {
    return __uint_as_float((unsigned int)u << 16);
}

// ---------------- workspace layout (bytes) ----------------
// WCT 0 (49152) | BC 49152 (192) | Z0 65536 (9.6e6, 3 chunks x NN x 16 bf16)
// ZA 9665536 | ZB 19265536 | DINV 28865536 | CNT 29265536 | PTR 29665664
// BSUM 30065792 | PTR2 30067840 | CEV 30467968 (+12.8e6) = 43.3 MB total

__global__ void wct_kernel(const float* __restrict__ W1, const float* __restrict__ W2,
                           const float* __restrict__ b1, short* __restrict__ WcT,
                           float* __restrict__ bc) {
    int t = blockIdx.x * 256 + threadIdx.x;
    if (t < 48 * 512) {
        int j = t >> 9, k = t & 511;
        float s = 0.f;
        if (j < 40)
            for (int i = 0; i < 128; ++i) s = fmaf(W1[k * 128 + i], W2[i * 40 + j], s);
        WcT[j * 512 + k] = (short)f2bfu(s);
    } else if (t < 48 * 512 + 48) {
        int j = t - 48 * 512;
        float s = 0.f;
        if (j < 40)
            for (int i = 0; i < 128; ++i) s = fmaf(b1[i], W2[i * 40 + j], s);
        bc[j] = s;
    }
}

// z0 = bf16( x @ Wc + bc ), written chunk-major: chunk c holds features c*16..c*16+15,
// row stride 16 (32 B). Features 40..47 are exact zeros (WcT/bc padded).
__global__ __launch_bounds__(256) void gemm_z0(const float* __restrict__ x,
                                               const short* __restrict__ WcT,
                                               const float* __restrict__ bc,
                                               unsigned short* __restrict__ z0) {
    const int tid = threadIdx.x;
    const int lane = tid & 63;
    const int wave = tid >> 6;
    const int rbase = blockIdx.x * 64 + wave * 16;
    const int row = rbase + (lane & 15);
    const int kc = lane >> 4;
    const bool rok = row < NN;

    f32x4 acc0 = {0.f, 0.f, 0.f, 0.f};
    f32x4 acc1 = {0.f, 0.f, 0.f, 0.f};
    f32x4 acc2 = {0.f, 0.f, 0.f, 0.f};

    const float* xrow = x + (size_t)row * 512 + kc * 8;
    const short* bp0 = WcT + (size_t)(lane & 15) * 512 + kc * 8;
    const short* bp1 = bp0 + 16 * 512;
    const short* bp2 = bp0 + 32 * 512;

    for (int k0 = 0; k0 < 512; k0 += 32) {
        float4 p0 = {0.f, 0.f, 0.f, 0.f}, p1 = {0.f, 0.f, 0.f, 0.f};
        if (rok) {
            p0 = *reinterpret_cast<const float4*>(xrow + k0);
            p1 = *reinterpret_cast<const float4*>(xrow + k0 + 4);
        }
        short8 a;
        a[0] = (short)f2bfu(p0.x); a[1] = (short)f2bfu(p0.y);
        a[2] = (short)f2bfu(p0.z); a[3] = (short)f2bfu(p0.w);
        a[4] = (short)f2bfu(p1.x); a[5] = (short)f2bfu(p1.y);
        a[6] = (short)f2bfu(p1.z); a[7] = (short)f2bfu(p1.w);
        short8 b0 = *reinterpret_cast<const short8*>(bp0 + k0);
        short8 b1 = *reinterpret_cast<const short8*>(bp1 + k0);
        short8 b2 = *reinterpret_cast<const short8*>(bp2 + k0);
        acc0 = __builtin_amdgcn_mfma_f32_16x16x32_bf16(a, b0, acc0, 0, 0, 0);
        acc1 = __builtin_amdgcn_mfma_f32_16x16x32_bf16(a, b1, acc1, 0, 0, 0);
        acc2 = __builtin_amdgcn_mfma_f32_16x16x32_bf16(a, b2, acc2, 0, 0, 0);
    }

    const int cb = lane & 15;
    const int rr = rbase + (lane >> 4) * 4;
#pragma unroll
    for (int q = 0; q < 4; ++q) {
        int r = rr + q;
        if (r < NN) {
            unsigned ro = ((unsigned)r << 4) + cb;
            z0[ro] = f2bfu(acc0[q] + bc[cb]);
            z0[CH_STRIDE + ro] = f2bfu(acc1[q] + bc[cb + 16]);
            z0[2 * CH_STRIDE + ro] = f2bfu(acc2[q] + bc[cb + 32]);
        }
    }
}

__global__ void count_kernel(const int* __restrict__ eidx, int* __restrict__ counts) {
    int e = blockIdx.x * 256 + threadIdx.x;
    if (e < EE) atomicAdd(&counts[eidx[EE + e]], 1);
}

__global__ void scan1(const int* __restrict__ counts, int* __restrict__ ptr,
                      int* __restrict__ bsum) {
    __shared__ int s[256];
    int tid = threadIdx.x;
    int i = blockIdx.x * 256 + tid;
    int v = (i < NN) ? counts[i] : 0;
    s[tid] = v;
    __syncthreads();
    for (int off = 1; off < 256; off <<= 1) {
        int t = (tid >= off) ? s[tid - off] : 0;
        __syncthreads();
        s[tid] += t;
        __syncthreads();
    }
    if (i < NN) ptr[i] = s[tid] - v;
    if (tid == 255) bsum[blockIdx.x] = s[255];
}

__global__ void scan2(int* __restrict__ bsum) {
    __shared__ int s[512];
    int tid = threadIdx.x;
    int v = (tid < 391) ? bsum[tid] : 0;
    s[tid] = v;
    __syncthreads();
    for (int off = 1; off < 512; off <<= 1) {
        int t = (tid >= off) ? s[tid - off] : 0;
        __syncthreads();
        s[tid] += t;
        __syncthreads();
    }
    if (tid < 391) bsum[tid] = s[tid] - v;
}

__global__ void scan3(int* __restrict__ ptr, const int* __restrict__ bsum,
                      const int* __restrict__ counts, float* __restrict__ dinvp,
                      int* __restrict__ ptr2) {
    int i = blockIdx.x * 256 + threadIdx.x;
    if (i < NN) {
        int p = ptr[i] + bsum[blockIdx.x];
        ptr[i] = p;
        ptr2[i] = p;
        dinvp[i] = rsqrtf(1.0f + (float)counts[i]);
    }
    if (i == 0) { ptr[NN] = EE; ptr2[NN] = EE; }
}

__global__ void scatter_kernel(const int* __restrict__ eidx,
                               const float* __restrict__ dinvp, int* __restrict__ ptr2,
                               int2* __restrict__ cev) {
    int e = blockIdx.x * 256 + threadIdx.x;
    if (e < EE) {
        int r = eidx[e];
        int c = eidx[EE + e];
        int pos = atomicAdd(&ptr2[c], 1);
        cev[pos] = make_int2(r, __float_as_int(dinvp[r]));
    }
}

// chunked propagate: 16 features/node (32 B row, 3.2 MB L2-resident state),
// 4 nodes/wave (16 lanes each, lane = feature, no cross-lane reduction).
// Branch-free to wave-max degree; weights zeroed past each node's degree.
__global__ __launch_bounds__(256) void propagate(const unsigned short* __restrict__ zcur,
                                                 const unsigned short* __restrict__ z0q,
                                                 unsigned short* __restrict__ znb,
                                                 float* __restrict__ outf,
                                                 const int* __restrict__ ptr,
                                                 const int2* __restrict__ cev,
                                                 const float* __restrict__ dinvp,
                                                 const float* __restrict__ b2,
                                                 int cid, int last) {
    const int lane = threadIdx.x & 63;
    const int f = lane & 15;
    const int g = lane >> 4;
    const int wid = blockIdx.x * 4 + (threadIdx.x >> 6);
    const int n = (wid << 2) + g;  // < 100000 (grid.x = 6250)

    const int beg = ptr[n];
    const int deg = ptr[n + 1] - beg;
    const float dc = dinvp[n];
    const unsigned roff = ((unsigned)n << 4) + f;

    float acc = dc * bf2f(zcur[roff]);
    const float z0v = bf2f(z0q[roff]);

    int maxd = deg;
    maxd = max(maxd, __shfl_xor(maxd, 16, 64));
    maxd = max(maxd, __shfl_xor(maxd, 32, 64));

    for (int s = 0; s < maxd; s += 4) {
        int i0, i1, i2, i3;
        {
            int t0 = (s + 0 < deg) ? s + 0 : deg - 1;
            int t1 = (s + 1 < deg) ? s + 1 : deg - 1;
            int t2 = (s + 2 < deg) ? s + 2 : deg - 1;
            int t3 = (s + 3 < deg) ? s + 3 : deg - 1;
            i0 = beg + t0; i0 = i0 < 0 ? 0 : (i0 >= EE ? EE - 1 : i0);
            i1 = beg + t1; i1 = i1 < 0 ? 0 : (i1 >= EE ? EE - 1 : i1);
            i2 = beg + t2; i2 = i2 < 0 ? 0 : (i2 >= EE ? EE - 1 : i2);
            i3 = beg + t3; i3 = i3 < 0 ? 0 : (i3 >= EE ? EE - 1 : i3);
        }
        int2 e0 = cev[i0];
        int2 e1 = cev[i1];
        int2 e2 = cev[i2];
        int2 e3 = cev[i3];
        float x0 = bf2f(zcur[((unsigned)e0.x << 4) + f]);
        float x1 = bf2f(zcur[((unsigned)e1.x << 4) + f]);
        float x2 = bf2f(zcur[((unsigned)e2.x << 4) + f]);
        float x3 = bf2f(zcur[((unsigned)e3.x << 4) + f]);
        float w0 = (s + 0 < deg) ? __int_as_float(e0.y) : 0.f;
        float w1 = (s + 1 < deg) ? __int_as_float(e1.y) : 0.f;
        float w2 = (s + 2 < deg) ? __int_as_float(e2.y) : 0.f;
        float w3 = (s + 3 < deg) ? __int_as_float(e3.y) : 0.f;
        acc = fmaf(w0, x0, acc);
        acc = fmaf(w1, x1, acc);
        acc = fmaf(w2, x2, acc);
        acc = fmaf(w3, x3, acc);
    }

    float res = 0.5f * dc * acc + 0.5f * z0v;
    if (last) {
        int j = cid * 16 + f;
        if (j < 40) outf[(unsigned)n * 40 + j] = res + b2[j];
    } else {
        znb[roff] = f2bfu(res);
    }
}

extern "C" void kernel_launch(void* const* d_in, const int* in_sizes, int n_in,
                              void* d_out, int out_size, void* d_ws, size_t ws_size,
                              hipStream_t stream) {
    const float* x  = (const float*)d_in[0];
    const int*   ei = (const int*)d_in[1];
    const float* W1 = (const float*)d_in[2];
    const float* b1 = (const float*)d_in[3];
    const float* W2 = (const float*)d_in[4];
    const float* b2 = (const float*)d_in[5];
    float* out = (float*)d_out;

    char* ws = (char*)d_ws;
    short*          WcT  = (short*)(ws + 0);
    float*          bc   = (float*)(ws + 49152);
    unsigned short* z0   = (unsigned short*)(ws + 65536);
    unsigned short* za   = (unsigned short*)(ws + 9665536);
    unsigned short* zb   = (unsigned short*)(ws + 19265536);
    float*          dinv = (float*)(ws + 28865536);
    int*            cnt  = (int*)(ws + 29265536);
    int*            ptr  = (int*)(ws + 29665664);
    int*            bsum = (int*)(ws + 30065792);
    int*            ptr2 = (int*)(ws + 30067840);
    int2*           cev  = (int2*)(ws + 30467968);

    hipMemsetAsync(cnt, 0, NN * sizeof(int), stream);
    wct_kernel<<<97, 256, 0, stream>>>(W1, W2, b1, WcT, bc);
    count_kernel<<<(EE + 255) / 256, 256, 0, stream>>>(ei, cnt);
    scan1<<<391, 256, 0, stream>>>(cnt, ptr, bsum);
    scan2<<<1, 512, 0, stream>>>(bsum);
    scan3<<<391, 256, 0, stream>>>(ptr, bsum, cnt, dinv, ptr2);
    gemm_z0<<<1563, 256, 0, stream>>>(x, WcT, bc, z0);
    scatter_kernel<<<(EE + 255) / 256, 256, 0, stream>>>(ei, dinv, ptr2, cev);

    // chunk-outer, iteration-inner: each chunk's 3.2 MB state stays L2-hot
    for (int c = 0; c < 3; ++c) {
        const unsigned short* z0c = z0 + (size_t)c * CH_STRIDE;
        unsigned short* zac = za + (size_t)c * CH_STRIDE;
        unsigned short* zbc = zb + (size_t)c * CH_STRIDE;
        propagate<<<6250, 256, 0, stream>>>(z0c, z0c, zbc, out, ptr, cev, dinv, b2, c, 0);
        propagate<<<6250, 256, 0, stream>>>(zbc, z0c, zac, out, ptr, cev, dinv, b2, c, 0);
        propagate<<<6250, 256, 0, stream>>>(zac, z0c, zbc, out, ptr, cev, dinv, b2, c, 0);
        propagate<<<6250, 256, 0, stream>>>(zbc, z0c, zac, out, ptr, cev, dinv, b2, c, 0);
        propagate<<<6250, 256, 0, stream>>>(zac, z0c, zbc, out, ptr, cev, dinv, b2, c, 1);
    }
}